// Round 1
// baseline (821.409 us; speedup 1.0000x reference)
//
#include <hip/hip_runtime.h>

// GAT encoder, 3 layers. N=50000, E=800000, Fin=128.
// Layer0/1: H=4 heads, C=32 (Fout=128), relu. Layer2: H=1, C=64, no relu.
//
// Pipeline per call:
//   CSR build (once, reused all layers): hist -> scan -> scatter (dst-sorted src list)
//   per layer: GEMM (h = feat @ W) -> alpha dots (asrc/adst per node,head)
//              -> wave-per-node aggregate (softmax over in-edges + weighted sum)

#define NEG_SLOPE 0.2f

__global__ void fill_zero_kernel(int* __restrict__ p, int n) {
    int i = blockIdx.x * blockDim.x + threadIdx.x;
    if (i < n) p[i] = 0;
}

__global__ void hist_kernel(const int* __restrict__ ei, int E, int* __restrict__ counts) {
    int i = blockIdx.x * blockDim.x + threadIdx.x;
    if (i < E) atomicAdd(&counts[ei[E + i]], 1);  // row 1 = dst
}

// Single-block exclusive scan over counts[N] -> offsets[N+1]; also seeds cursor.
__global__ __launch_bounds__(1024) void scan_kernel(const int* __restrict__ counts,
                                                    int* __restrict__ offsets,
                                                    int* __restrict__ cursor, int N) {
    __shared__ int sums[1024];
    int tid = threadIdx.x;
    int chunk = (N + 1023) / 1024;
    int begin = tid * chunk;
    int end = begin + chunk;
    if (begin > N) begin = N;
    if (end > N) end = N;
    int s = 0;
    for (int i = begin; i < end; ++i) s += counts[i];
    sums[tid] = s;
    __syncthreads();
    for (int off = 1; off < 1024; off <<= 1) {
        int v = (tid >= off) ? sums[tid - off] : 0;
        __syncthreads();
        sums[tid] += v;
        __syncthreads();
    }
    int prefix = (tid == 0) ? 0 : sums[tid - 1];
    for (int i = begin; i < end; ++i) {
        offsets[i] = prefix;
        cursor[i] = prefix;
        prefix += counts[i];
    }
    if (tid == 1023) offsets[N] = sums[1023];
}

__global__ void scatter_kernel(const int* __restrict__ ei, int E,
                               int* __restrict__ cursor, int* __restrict__ ssrc) {
    int i = blockIdx.x * blockDim.x + threadIdx.x;
    if (i < E) {
        int dst = ei[E + i];
        int pos = atomicAdd(&cursor[dst], 1);
        ssrc[pos] = ei[i];  // row 0 = src
    }
}

// H = X @ W.  X:[N,128], W:[128,FOUT], H:[N,FOUT].  fp32 vector GEMM.
// Block: 256 threads, 32 rows. Each thread: JN rows x 4 cols register tile.
template <int FOUT>
__global__ __launch_bounds__(256) void gemm_kernel(const float* __restrict__ X,
                                                   const float* __restrict__ W,
                                                   float* __restrict__ H, int N) {
    constexpr int ROWS = 32;
    constexpr int CQ = FOUT / 4;       // threads per row-group
    constexpr int G = 256 / CQ;        // row-groups
    constexpr int JN = ROWS / G;       // rows per thread
    __shared__ float xs[ROWS][128];    // 16 KB
    __shared__ float ws[64][FOUT];     // 32 KB (FOUT=128) / 16 KB

    int tid = threadIdx.x;
    int row0 = blockIdx.x * ROWS;

    // stage x tile (32x128 floats = 1024 float4)
#pragma unroll
    for (int i = 0; i < 4; ++i) {
        int f = tid + i * 256;
        int r = f >> 5, k4 = f & 31;
        int row = row0 + r;
        if (row >= N) row = N - 1;  // clamp: garbage rows never stored
        *(float4*)&xs[r][k4 * 4] = *(const float4*)&X[(size_t)row * 128 + k4 * 4];
    }

    int c = tid % CQ;
    int jg = tid / CQ;
    float acc[JN][4];
#pragma unroll
    for (int j = 0; j < JN; ++j)
#pragma unroll
        for (int q = 0; q < 4; ++q) acc[j][q] = 0.f;

    for (int kh = 0; kh < 2; ++kh) {
        __syncthreads();
        // stage W rows [kh*64, kh*64+64)
        for (int f = tid; f < 64 * (FOUT / 4); f += 256) {
            int kk = f / (FOUT / 4), c4 = f % (FOUT / 4);
            *(float4*)&ws[kk][c4 * 4] =
                *(const float4*)&W[(size_t)(kh * 64 + kk) * FOUT + c4 * 4];
        }
        __syncthreads();
#pragma unroll
        for (int k4 = 0; k4 < 16; ++k4) {
            float4 xv[JN];
#pragma unroll
            for (int j = 0; j < JN; ++j)
                xv[j] = *(float4*)&xs[jg * JN + j][kh * 64 + k4 * 4];
#pragma unroll
            for (int kk = 0; kk < 4; ++kk) {
                int k = k4 * 4 + kk;
                float w0 = ws[k][c], w1 = ws[k][c + CQ], w2 = ws[k][c + 2 * CQ],
                      w3 = ws[k][c + 3 * CQ];
#pragma unroll
                for (int j = 0; j < JN; ++j) {
                    float xx = (kk == 0) ? xv[j].x : (kk == 1) ? xv[j].y
                                         : (kk == 2) ? xv[j].z : xv[j].w;
                    acc[j][0] += xx * w0;
                    acc[j][1] += xx * w1;
                    acc[j][2] += xx * w2;
                    acc[j][3] += xx * w3;
                }
            }
        }
    }
#pragma unroll
    for (int j = 0; j < JN; ++j) {
        int row = row0 + jg * JN + j;
        if (row < N) {
            H[(size_t)row * FOUT + c] = acc[j][0];
            H[(size_t)row * FOUT + c + CQ] = acc[j][1];
            H[(size_t)row * FOUT + c + 2 * CQ] = acc[j][2];
            H[(size_t)row * FOUT + c + 3 * CQ] = acc[j][3];
        }
    }
}

// asrc[n,h] = dot(h[n,h,:], a_src[h,:]); adst likewise.
template <int H_, int C>
__global__ void alpha_kernel(const float* __restrict__ hbuf, const float* __restrict__ a_src,
                             const float* __restrict__ a_dst, float* __restrict__ asrc,
                             float* __restrict__ adst, int N) {
    int idx = blockIdx.x * blockDim.x + threadIdx.x;
    if (idx >= N * H_) return;
    int n = idx / H_, h = idx % H_;
    const float* hp = &hbuf[(size_t)n * H_ * C + h * C];
    const float* as = &a_src[h * C];
    const float* ad = &a_dst[h * C];
    float s1 = 0.f, s2 = 0.f;
#pragma unroll
    for (int c4 = 0; c4 < C / 4; ++c4) {
        float4 v = *(const float4*)&hp[c4 * 4];
        float4 u = *(const float4*)&as[c4 * 4];
        float4 w = *(const float4*)&ad[c4 * 4];
        s1 += v.x * u.x + v.y * u.y + v.z * u.z + v.w * u.w;
        s2 += v.x * w.x + v.y * w.y + v.z * w.z + v.w * w.w;
    }
    asrc[idx] = s1;
    adst[idx] = s2;
}

// One wave per destination node: segment softmax + weighted aggregation, no atomics.
// Self-loop folded in (src = n). PER = FOUT/64 channels per lane.
template <int H_, int C, bool RELU>
__global__ __launch_bounds__(256) void aggr_kernel(
    const float* __restrict__ hbuf, const float* __restrict__ asrc,
    const float* __restrict__ adst, const float* __restrict__ bias,
    const int* __restrict__ offsets, const int* __restrict__ ssrc,
    float* __restrict__ out, int N) {
    constexpr int FOUT = H_ * C;
    constexpr int PER = FOUT / 64;  // 2 (128) or 1 (64)
    int wid = threadIdx.x >> 6;
    int lane = threadIdx.x & 63;
    int n = blockIdx.x * 4 + wid;
    if (n >= N) return;
    int c0 = lane * PER;
    int head = c0 / C;

    float adst_h = adst[n * H_ + head];
    float eself = asrc[n * H_ + head] + adst_h;
    eself = eself > 0.f ? eself : NEG_SLOPE * eself;

    int e0 = offsets[n], e1 = offsets[n + 1];

    // pass 1: max
    float m = eself;
    for (int k = e0; k < e1; ++k) {
        int s = ssrc[k];
        float e = asrc[s * H_ + head] + adst_h;
        e = e > 0.f ? e : NEG_SLOPE * e;
        m = fmaxf(m, e);
    }

    // pass 2: denom + weighted sum (self first)
    float exs = __expf(eself - m);
    float D = exs;
    float S0, S1 = 0.f;
    if (PER == 2) {
        float2 hv = *(const float2*)&hbuf[(size_t)n * FOUT + c0];
        S0 = exs * hv.x;
        S1 = exs * hv.y;
    } else {
        S0 = exs * hbuf[(size_t)n * FOUT + c0];
    }
    for (int k = e0; k < e1; ++k) {
        int s = ssrc[k];
        float e = asrc[s * H_ + head] + adst_h;
        e = e > 0.f ? e : NEG_SLOPE * e;
        float ex = __expf(e - m);
        D += ex;
        if (PER == 2) {
            float2 hv = *(const float2*)&hbuf[(size_t)s * FOUT + c0];
            S0 += ex * hv.x;
            S1 += ex * hv.y;
        } else {
            S0 += ex * hbuf[(size_t)s * FOUT + c0];
        }
    }

    float inv = 1.f / (D + 1e-16f);
    float v0 = S0 * inv + bias[c0];
    if (RELU) v0 = fmaxf(v0, 0.f);
    if (PER == 2) {
        float v1 = S1 * inv + bias[c0 + 1];
        if (RELU) v1 = fmaxf(v1, 0.f);
        *(float2*)&out[(size_t)n * FOUT + c0] = make_float2(v0, v1);
    } else {
        out[(size_t)n * FOUT + c0] = v0;
    }
}

extern "C" void kernel_launch(void* const* d_in, const int* in_sizes, int n_in,
                              void* d_out, int out_size, void* d_ws, size_t ws_size,
                              hipStream_t stream) {
    const float* x = (const float*)d_in[0];
    const int* ei = (const int*)d_in[1];
    const float* W0 = (const float*)d_in[2];
    const float* as0 = (const float*)d_in[3];
    const float* ad0 = (const float*)d_in[4];
    const float* b0 = (const float*)d_in[5];
    const float* W1 = (const float*)d_in[6];
    const float* as1 = (const float*)d_in[7];
    const float* ad1 = (const float*)d_in[8];
    const float* b1 = (const float*)d_in[9];
    const float* W2 = (const float*)d_in[10];
    const float* as2 = (const float*)d_in[11];
    const float* ad2 = (const float*)d_in[12];
    const float* b2 = (const float*)d_in[13];

    const int N = in_sizes[0] / 128;  // 50000
    const int E = in_sizes[1] / 2;    // 800000

    // workspace carve (~57 MB)
    float* wsf = (float*)d_ws;
    float* hbuf = wsf;                         // N*128
    float* feat = hbuf + (size_t)N * 128;      // N*128
    float* aS = feat + (size_t)N * 128;        // N*4
    float* aD = aS + (size_t)N * 4;            // N*4
    int* counts = (int*)(aD + (size_t)N * 4);  // N
    int* offsets = counts + N;                 // N+1
    int* cursor = offsets + N + 1;             // N
    int* ssrc = cursor + N;                    // E

    // ---- CSR build (dst-sorted srcs), reused by all 3 layers ----
    fill_zero_kernel<<<(N + 255) / 256, 256, 0, stream>>>(counts, N);
    hist_kernel<<<(E + 255) / 256, 256, 0, stream>>>(ei, E, counts);
    scan_kernel<<<1, 1024, 0, stream>>>(counts, offsets, cursor, N);
    scatter_kernel<<<(E + 255) / 256, 256, 0, stream>>>(ei, E, cursor, ssrc);

    const int gGemm = (N + 31) / 32;
    const int gAggr = (N + 3) / 4;

    // ---- layer 0 ----
    gemm_kernel<128><<<gGemm, 256, 0, stream>>>(x, W0, hbuf, N);
    alpha_kernel<4, 32><<<(N * 4 + 255) / 256, 256, 0, stream>>>(hbuf, as0, ad0, aS, aD, N);
    aggr_kernel<4, 32, true><<<gAggr, 256, 0, stream>>>(hbuf, aS, aD, b0, offsets, ssrc, feat, N);

    // ---- layer 1 ----
    gemm_kernel<128><<<gGemm, 256, 0, stream>>>(feat, W1, hbuf, N);
    alpha_kernel<4, 32><<<(N * 4 + 255) / 256, 256, 0, stream>>>(hbuf, as1, ad1, aS, aD, N);
    aggr_kernel<4, 32, true><<<gAggr, 256, 0, stream>>>(hbuf, aS, aD, b1, offsets, ssrc, feat, N);

    // ---- layer 2 ----
    gemm_kernel<64><<<gGemm, 256, 0, stream>>>(feat, W2, hbuf, N);
    alpha_kernel<1, 64><<<(N + 255) / 256, 256, 0, stream>>>(hbuf, as2, ad2, aS, aD, N);
    aggr_kernel<1, 64, false><<<gAggr, 256, 0, stream>>>(hbuf, aS, aD, b2, offsets, ssrc,
                                                         (float*)d_out, N);
}

// Round 2
// 570.259 us; speedup vs baseline: 1.4404x; 1.4404x over previous
//
#include <hip/hip_runtime.h>

// GAT encoder, 3 layers. N=50000, E=800000, Fin=128.
// Layer0/1: H=4 heads, C=32 (Fout=128), relu. Layer2: H=1, C=64, no relu.
//
// R1 -> R2 changes:
//  * aggr_kernel: fused online-softmax single pass (was 2 passes) + 4x edge
//    unroll with h-row gathers issued immediately after ssrc loads (MLP).
//  * gemm_kernel: each thread owns a contiguous 4-col quad -> ds_read_b128
//    W reads + dwordx4 C stores (was 16 scalar b32 reads per k4).

#define NEG_SLOPE 0.2f

__device__ __forceinline__ float lrelu(float v) { return v > 0.f ? v : NEG_SLOPE * v; }

__global__ void fill_zero_kernel(int* __restrict__ p, int n) {
    int i = blockIdx.x * blockDim.x + threadIdx.x;
    if (i < n) p[i] = 0;
}

__global__ void hist_kernel(const int* __restrict__ ei, int E, int* __restrict__ counts) {
    int i = blockIdx.x * blockDim.x + threadIdx.x;
    if (i < E) atomicAdd(&counts[ei[E + i]], 1);  // row 1 = dst
}

// Single-block exclusive scan over counts[N] -> offsets[N+1]; also seeds cursor.
__global__ __launch_bounds__(1024) void scan_kernel(const int* __restrict__ counts,
                                                    int* __restrict__ offsets,
                                                    int* __restrict__ cursor, int N) {
    __shared__ int sums[1024];
    int tid = threadIdx.x;
    int chunk = (N + 1023) / 1024;
    int begin = tid * chunk;
    int end = begin + chunk;
    if (begin > N) begin = N;
    if (end > N) end = N;
    int s = 0;
    for (int i = begin; i < end; ++i) s += counts[i];
    sums[tid] = s;
    __syncthreads();
    for (int off = 1; off < 1024; off <<= 1) {
        int v = (tid >= off) ? sums[tid - off] : 0;
        __syncthreads();
        sums[tid] += v;
        __syncthreads();
    }
    int prefix = (tid == 0) ? 0 : sums[tid - 1];
    for (int i = begin; i < end; ++i) {
        offsets[i] = prefix;
        cursor[i] = prefix;
        prefix += counts[i];
    }
    if (tid == 1023) offsets[N] = sums[1023];
}

__global__ void scatter_kernel(const int* __restrict__ ei, int E,
                               int* __restrict__ cursor, int* __restrict__ ssrc) {
    int i = blockIdx.x * blockDim.x + threadIdx.x;
    if (i < E) {
        int dst = ei[E + i];
        int pos = atomicAdd(&cursor[dst], 1);
        ssrc[pos] = ei[i];  // row 0 = src
    }
}

// H = X @ W.  X:[N,128], W:[128,FOUT], H:[N,FOUT].  fp32 vector GEMM.
// Block: 256 threads, 32 rows. Thread (c,jg): JN rows x contiguous 4-col quad.
template <int FOUT>
__global__ __launch_bounds__(256) void gemm_kernel(const float* __restrict__ X,
                                                   const float* __restrict__ W,
                                                   float* __restrict__ H, int N) {
    constexpr int ROWS = 32;
    constexpr int CQ = FOUT / 4;       // col-quads per row: 32 or 16
    constexpr int G = 256 / CQ;        // row-groups: 8 or 16
    constexpr int JN = ROWS / G;       // rows per thread: 4 or 2
    __shared__ float xs[ROWS][128];    // 16 KB
    __shared__ float ws[64][FOUT];     // 32 KB (FOUT=128) / 16 KB

    int tid = threadIdx.x;
    int row0 = blockIdx.x * ROWS;

    // stage x tile (32x128 floats = 1024 float4)
#pragma unroll
    for (int i = 0; i < 4; ++i) {
        int f = tid + i * 256;
        int r = f >> 5, k4 = f & 31;
        int row = row0 + r;
        if (row >= N) row = N - 1;  // clamp: garbage rows never stored
        *(float4*)&xs[r][k4 * 4] = *(const float4*)&X[(size_t)row * 128 + k4 * 4];
    }

    int c = tid % CQ;
    int jg = tid / CQ;
    float4 acc[JN];
#pragma unroll
    for (int j = 0; j < JN; ++j) acc[j] = make_float4(0.f, 0.f, 0.f, 0.f);

    for (int kh = 0; kh < 2; ++kh) {
        __syncthreads();
        // stage W rows [kh*64, kh*64+64)
        for (int f = tid; f < 64 * (FOUT / 4); f += 256) {
            int kk = f / (FOUT / 4), c4 = f % (FOUT / 4);
            *(float4*)&ws[kk][c4 * 4] =
                *(const float4*)&W[(size_t)(kh * 64 + kk) * FOUT + c4 * 4];
        }
        __syncthreads();
#pragma unroll
        for (int k4 = 0; k4 < 16; ++k4) {
            float4 xv[JN];
#pragma unroll
            for (int j = 0; j < JN; ++j)
                xv[j] = *(float4*)&xs[jg * JN + j][kh * 64 + k4 * 4];
#pragma unroll
            for (int kk = 0; kk < 4; ++kk) {
                float4 wv = *(float4*)&ws[k4 * 4 + kk][c * 4];
#pragma unroll
                for (int j = 0; j < JN; ++j) {
                    float xx = (kk == 0) ? xv[j].x : (kk == 1) ? xv[j].y
                                         : (kk == 2) ? xv[j].z : xv[j].w;
                    acc[j].x += xx * wv.x;
                    acc[j].y += xx * wv.y;
                    acc[j].z += xx * wv.z;
                    acc[j].w += xx * wv.w;
                }
            }
        }
    }
#pragma unroll
    for (int j = 0; j < JN; ++j) {
        int row = row0 + jg * JN + j;
        if (row < N) *(float4*)&H[(size_t)row * FOUT + c * 4] = acc[j];
    }
}

// asrc[n,h] = dot(h[n,h,:], a_src[h,:]); adst likewise.
template <int H_, int C>
__global__ void alpha_kernel(const float* __restrict__ hbuf, const float* __restrict__ a_src,
                             const float* __restrict__ a_dst, float* __restrict__ asrc,
                             float* __restrict__ adst, int N) {
    int idx = blockIdx.x * blockDim.x + threadIdx.x;
    if (idx >= N * H_) return;
    int n = idx / H_, h = idx % H_;
    const float* hp = &hbuf[(size_t)n * H_ * C + h * C];
    const float* as = &a_src[h * C];
    const float* ad = &a_dst[h * C];
    float s1 = 0.f, s2 = 0.f;
#pragma unroll
    for (int c4 = 0; c4 < C / 4; ++c4) {
        float4 v = *(const float4*)&hp[c4 * 4];
        float4 u = *(const float4*)&as[c4 * 4];
        float4 w = *(const float4*)&ad[c4 * 4];
        s1 += v.x * u.x + v.y * u.y + v.z * u.z + v.w * u.w;
        s2 += v.x * w.x + v.y * w.y + v.z * w.z + v.w * w.w;
    }
    asrc[idx] = s1;
    adst[idx] = s2;
}

// One wave per destination node: fused online-softmax aggregation, no atomics.
// Self-loop folded in (src = n). PER = FOUT/64 channels per lane.
// 4x edge unroll; h-row gathers issued right after ssrc loads for MLP.
template <int H_, int C, bool RELU>
__global__ __launch_bounds__(256) void aggr_kernel(
    const float* __restrict__ hbuf, const float* __restrict__ asrc,
    const float* __restrict__ adst, const float* __restrict__ bias,
    const int* __restrict__ offsets, const int* __restrict__ ssrc,
    float* __restrict__ out, int N) {
    constexpr int FOUT = H_ * C;
    constexpr int PER = FOUT / 64;  // 2 (128) or 1 (64)
    int wid = threadIdx.x >> 6;
    int lane = threadIdx.x & 63;
    int n = blockIdx.x * 4 + wid;
    if (n >= N) return;
    int c0 = lane * PER;
    int head = c0 / C;

    float adst_h = adst[n * H_ + head];
    // self edge first: m = e_self, exp(e_self - m) = 1
    float m = lrelu(asrc[n * H_ + head] + adst_h);
    float D = 1.f;
    float S0, S1 = 0.f;
    if (PER == 2) {
        float2 hv = *(const float2*)&hbuf[(size_t)n * FOUT + c0];
        S0 = hv.x;
        S1 = hv.y;
    } else {
        S0 = hbuf[(size_t)n * FOUT + c0];
    }

    int k = offsets[n];
    const int e1 = offsets[n + 1];

    for (; k + 4 <= e1; k += 4) {
        int s0 = ssrc[k], s1 = ssrc[k + 1], s2 = ssrc[k + 2], s3 = ssrc[k + 3];
        // issue the heavy gathers early (depend only on s)
        float2 h0, h1, h2, h3;
        float g0 = 0.f, g1 = 0.f, g2 = 0.f, g3 = 0.f;
        if (PER == 2) {
            h0 = *(const float2*)&hbuf[(size_t)s0 * FOUT + c0];
            h1 = *(const float2*)&hbuf[(size_t)s1 * FOUT + c0];
            h2 = *(const float2*)&hbuf[(size_t)s2 * FOUT + c0];
            h3 = *(const float2*)&hbuf[(size_t)s3 * FOUT + c0];
        } else {
            g0 = hbuf[(size_t)s0 * FOUT + c0];
            g1 = hbuf[(size_t)s1 * FOUT + c0];
            g2 = hbuf[(size_t)s2 * FOUT + c0];
            g3 = hbuf[(size_t)s3 * FOUT + c0];
        }
        float E0 = lrelu(asrc[s0 * H_ + head] + adst_h);
        float E1 = lrelu(asrc[s1 * H_ + head] + adst_h);
        float E2 = lrelu(asrc[s2 * H_ + head] + adst_h);
        float E3 = lrelu(asrc[s3 * H_ + head] + adst_h);
        float mn = fmaxf(m, fmaxf(fmaxf(E0, E1), fmaxf(E2, E3)));
        float sc = __expf(m - mn);
        m = mn;
        D *= sc;
        S0 *= sc;
        if (PER == 2) S1 *= sc;
        float x0 = __expf(E0 - m), x1 = __expf(E1 - m);
        float x2 = __expf(E2 - m), x3 = __expf(E3 - m);
        D += (x0 + x1) + (x2 + x3);
        if (PER == 2) {
            S0 += x0 * h0.x + x1 * h1.x + x2 * h2.x + x3 * h3.x;
            S1 += x0 * h0.y + x1 * h1.y + x2 * h2.y + x3 * h3.y;
        } else {
            S0 += x0 * g0 + x1 * g1 + x2 * g2 + x3 * g3;
        }
    }
    for (; k < e1; ++k) {
        int s = ssrc[k];
        float2 hv;
        float gv = 0.f;
        if (PER == 2) {
            hv = *(const float2*)&hbuf[(size_t)s * FOUT + c0];
        } else {
            gv = hbuf[(size_t)s * FOUT + c0];
        }
        float E = lrelu(asrc[s * H_ + head] + adst_h);
        float mn = fmaxf(m, E);
        float sc = __expf(m - mn);
        m = mn;
        D *= sc;
        S0 *= sc;
        if (PER == 2) S1 *= sc;
        float ex = __expf(E - m);
        D += ex;
        if (PER == 2) {
            S0 += ex * hv.x;
            S1 += ex * hv.y;
        } else {
            S0 += ex * gv;
        }
    }

    float inv = 1.f / (D + 1e-16f);
    float v0 = S0 * inv + bias[c0];
    if (RELU) v0 = fmaxf(v0, 0.f);
    if (PER == 2) {
        float v1 = S1 * inv + bias[c0 + 1];
        if (RELU) v1 = fmaxf(v1, 0.f);
        *(float2*)&out[(size_t)n * FOUT + c0] = make_float2(v0, v1);
    } else {
        out[(size_t)n * FOUT + c0] = v0;
    }
}

extern "C" void kernel_launch(void* const* d_in, const int* in_sizes, int n_in,
                              void* d_out, int out_size, void* d_ws, size_t ws_size,
                              hipStream_t stream) {
    const float* x = (const float*)d_in[0];
    const int* ei = (const int*)d_in[1];
    const float* W0 = (const float*)d_in[2];
    const float* as0 = (const float*)d_in[3];
    const float* ad0 = (const float*)d_in[4];
    const float* b0 = (const float*)d_in[5];
    const float* W1 = (const float*)d_in[6];
    const float* as1 = (const float*)d_in[7];
    const float* ad1 = (const float*)d_in[8];
    const float* b1 = (const float*)d_in[9];
    const float* W2 = (const float*)d_in[10];
    const float* as2 = (const float*)d_in[11];
    const float* ad2 = (const float*)d_in[12];
    const float* b2 = (const float*)d_in[13];

    const int N = in_sizes[0] / 128;  // 50000
    const int E = in_sizes[1] / 2;    // 800000

    // workspace carve (~57 MB)
    float* wsf = (float*)d_ws;
    float* hbuf = wsf;                         // N*128
    float* feat = hbuf + (size_t)N * 128;      // N*128
    float* aS = feat + (size_t)N * 128;        // N*4
    float* aD = aS + (size_t)N * 4;            // N*4
    int* counts = (int*)(aD + (size_t)N * 4);  // N
    int* offsets = counts + N;                 // N+1
    int* cursor = offsets + N + 1;             // N
    int* ssrc = cursor + N;                    // E

    // ---- CSR build (dst-sorted srcs), reused by all 3 layers ----
    fill_zero_kernel<<<(N + 255) / 256, 256, 0, stream>>>(counts, N);
    hist_kernel<<<(E + 255) / 256, 256, 0, stream>>>(ei, E, counts);
    scan_kernel<<<1, 1024, 0, stream>>>(counts, offsets, cursor, N);
    scatter_kernel<<<(E + 255) / 256, 256, 0, stream>>>(ei, E, cursor, ssrc);

    const int gGemm = (N + 31) / 32;
    const int gAggr = (N + 3) / 4;

    // ---- layer 0 ----
    gemm_kernel<128><<<gGemm, 256, 0, stream>>>(x, W0, hbuf, N);
    alpha_kernel<4, 32><<<(N * 4 + 255) / 256, 256, 0, stream>>>(hbuf, as0, ad0, aS, aD, N);
    aggr_kernel<4, 32, true><<<gAggr, 256, 0, stream>>>(hbuf, aS, aD, b0, offsets, ssrc, feat, N);

    // ---- layer 1 ----
    gemm_kernel<128><<<gGemm, 256, 0, stream>>>(feat, W1, hbuf, N);
    alpha_kernel<4, 32><<<(N * 4 + 255) / 256, 256, 0, stream>>>(hbuf, as1, ad1, aS, aD, N);
    aggr_kernel<4, 32, true><<<gAggr, 256, 0, stream>>>(hbuf, aS, aD, b1, offsets, ssrc, feat, N);

    // ---- layer 2 ----
    gemm_kernel<64><<<gGemm, 256, 0, stream>>>(feat, W2, hbuf, N);
    alpha_kernel<1, 64><<<(N + 255) / 256, 256, 0, stream>>>(hbuf, as2, ad2, aS, aD, N);
    aggr_kernel<1, 64, false><<<gAggr, 256, 0, stream>>>(hbuf, aS, aD, b2, offsets, ssrc,
                                                         (float*)d_out, N);
}

// Round 3
// 465.576 us; speedup vs baseline: 1.7643x; 1.2248x over previous
//
#include <hip/hip_runtime.h>

// GAT encoder, 3 layers. N=50000, E=800000, Fin=128.
// Layer0/1: H=4 heads, C=32 (Fout=128), relu. Layer2: H=1, C=64, no relu.
//
// R2 -> R3: replace the single-block scan_kernel (111 us, 1 CU, 0.14% occ)
// with a 3-stage grid-wide scan (block_reduce -> scan_bsums -> write_offsets),
// each stage fully parallel. aggr/gemm unchanged from R2.

#define NEG_SLOPE 0.2f

__device__ __forceinline__ float lrelu(float v) { return v > 0.f ? v : NEG_SLOPE * v; }

__global__ void fill_zero_kernel(int* __restrict__ p, int n) {
    int i = blockIdx.x * blockDim.x + threadIdx.x;
    if (i < n) p[i] = 0;
}

__global__ void hist_kernel(const int* __restrict__ ei, int E, int* __restrict__ counts) {
    int i = blockIdx.x * blockDim.x + threadIdx.x;
    if (i < E) atomicAdd(&counts[ei[E + i]], 1);  // row 1 = dst
}

// Stage 1: per-block sum of 256 counts.
__global__ __launch_bounds__(256) void block_reduce_kernel(const int* __restrict__ counts,
                                                           int N, int* __restrict__ bsums) {
    int i = blockIdx.x * 256 + threadIdx.x;
    int v = (i < N) ? counts[i] : 0;
#pragma unroll
    for (int off = 32; off > 0; off >>= 1) v += __shfl_xor(v, off);
    __shared__ int ws[4];
    if ((threadIdx.x & 63) == 0) ws[threadIdx.x >> 6] = v;
    __syncthreads();
    if (threadIdx.x == 0) bsums[blockIdx.x] = ws[0] + ws[1] + ws[2] + ws[3];
}

// Stage 2: exclusive scan of nb block sums (nb <= 256*chunk), single small block.
__global__ __launch_bounds__(256) void scan_bsums_kernel(const int* __restrict__ bsums, int nb,
                                                         int* __restrict__ bpre,
                                                         int* __restrict__ offsets, int N) {
    int tid = threadIdx.x;
    int chunk = (nb + 255) / 256;
    int b0 = tid * chunk, b1 = b0 + chunk;
    if (b0 > nb) b0 = nb;
    if (b1 > nb) b1 = nb;
    int s = 0;
    for (int i = b0; i < b1; ++i) s += bsums[i];
    int v = s;
    int lane = tid & 63, wid = tid >> 6;
#pragma unroll
    for (int off = 1; off < 64; off <<= 1) {
        int t = __shfl_up(v, off);
        if (lane >= off) v += t;
    }
    __shared__ int ws[4];
    if (lane == 63) ws[wid] = v;
    __syncthreads();
    int add = 0;
    for (int w = 0; w < wid; ++w) add += ws[w];
    v += add;           // inclusive scan of per-thread chunk sums
    int prefix = v - s; // exclusive
    for (int i = b0; i < b1; ++i) {
        bpre[i] = prefix;
        prefix += bsums[i];
    }
    if (tid == 255) offsets[N] = v;  // grand total = E
}

// Stage 3: block-local exclusive scan + block prefix -> offsets, cursor.
__global__ __launch_bounds__(256) void write_offsets_kernel(const int* __restrict__ counts,
                                                            int N, const int* __restrict__ bpre,
                                                            int* __restrict__ offsets,
                                                            int* __restrict__ cursor) {
    int i = blockIdx.x * 256 + threadIdx.x;
    int orig = (i < N) ? counts[i] : 0;
    int v = orig;
    int lane = threadIdx.x & 63, wid = threadIdx.x >> 6;
#pragma unroll
    for (int off = 1; off < 64; off <<= 1) {
        int t = __shfl_up(v, off);
        if (lane >= off) v += t;
    }
    __shared__ int ws[4];
    if (lane == 63) ws[wid] = v;
    __syncthreads();
    int add = bpre[blockIdx.x];
    for (int w = 0; w < wid; ++w) add += ws[w];
    int exc = v - orig + add;
    if (i < N) {
        offsets[i] = exc;
        cursor[i] = exc;
    }
}

__global__ void scatter_kernel(const int* __restrict__ ei, int E,
                               int* __restrict__ cursor, int* __restrict__ ssrc) {
    int i = blockIdx.x * blockDim.x + threadIdx.x;
    if (i < E) {
        int dst = ei[E + i];
        int pos = atomicAdd(&cursor[dst], 1);
        ssrc[pos] = ei[i];  // row 0 = src
    }
}

// H = X @ W.  X:[N,128], W:[128,FOUT], H:[N,FOUT].  fp32 vector GEMM.
// Block: 256 threads, 32 rows. Thread (c,jg): JN rows x contiguous 4-col quad.
template <int FOUT>
__global__ __launch_bounds__(256) void gemm_kernel(const float* __restrict__ X,
                                                   const float* __restrict__ W,
                                                   float* __restrict__ H, int N) {
    constexpr int ROWS = 32;
    constexpr int CQ = FOUT / 4;
    constexpr int G = 256 / CQ;
    constexpr int JN = ROWS / G;
    __shared__ float xs[ROWS][128];
    __shared__ float ws[64][FOUT];

    int tid = threadIdx.x;
    int row0 = blockIdx.x * ROWS;

#pragma unroll
    for (int i = 0; i < 4; ++i) {
        int f = tid + i * 256;
        int r = f >> 5, k4 = f & 31;
        int row = row0 + r;
        if (row >= N) row = N - 1;
        *(float4*)&xs[r][k4 * 4] = *(const float4*)&X[(size_t)row * 128 + k4 * 4];
    }

    int c = tid % CQ;
    int jg = tid / CQ;
    float4 acc[JN];
#pragma unroll
    for (int j = 0; j < JN; ++j) acc[j] = make_float4(0.f, 0.f, 0.f, 0.f);

    for (int kh = 0; kh < 2; ++kh) {
        __syncthreads();
        for (int f = tid; f < 64 * (FOUT / 4); f += 256) {
            int kk = f / (FOUT / 4), c4 = f % (FOUT / 4);
            *(float4*)&ws[kk][c4 * 4] =
                *(const float4*)&W[(size_t)(kh * 64 + kk) * FOUT + c4 * 4];
        }
        __syncthreads();
#pragma unroll
        for (int k4 = 0; k4 < 16; ++k4) {
            float4 xv[JN];
#pragma unroll
            for (int j = 0; j < JN; ++j)
                xv[j] = *(float4*)&xs[jg * JN + j][kh * 64 + k4 * 4];
#pragma unroll
            for (int kk = 0; kk < 4; ++kk) {
                float4 wv = *(float4*)&ws[k4 * 4 + kk][c * 4];
#pragma unroll
                for (int j = 0; j < JN; ++j) {
                    float xx = (kk == 0) ? xv[j].x : (kk == 1) ? xv[j].y
                                         : (kk == 2) ? xv[j].z : xv[j].w;
                    acc[j].x += xx * wv.x;
                    acc[j].y += xx * wv.y;
                    acc[j].z += xx * wv.z;
                    acc[j].w += xx * wv.w;
                }
            }
        }
    }
#pragma unroll
    for (int j = 0; j < JN; ++j) {
        int row = row0 + jg * JN + j;
        if (row < N) *(float4*)&H[(size_t)row * FOUT + c * 4] = acc[j];
    }
}

// asrc[n,h] = dot(h[n,h,:], a_src[h,:]); adst likewise.
template <int H_, int C>
__global__ void alpha_kernel(const float* __restrict__ hbuf, const float* __restrict__ a_src,
                             const float* __restrict__ a_dst, float* __restrict__ asrc,
                             float* __restrict__ adst, int N) {
    int idx = blockIdx.x * blockDim.x + threadIdx.x;
    if (idx >= N * H_) return;
    int n = idx / H_, h = idx % H_;
    const float* hp = &hbuf[(size_t)n * H_ * C + h * C];
    const float* as = &a_src[h * C];
    const float* ad = &a_dst[h * C];
    float s1 = 0.f, s2 = 0.f;
#pragma unroll
    for (int c4 = 0; c4 < C / 4; ++c4) {
        float4 v = *(const float4*)&hp[c4 * 4];
        float4 u = *(const float4*)&as[c4 * 4];
        float4 w = *(const float4*)&ad[c4 * 4];
        s1 += v.x * u.x + v.y * u.y + v.z * u.z + v.w * u.w;
        s2 += v.x * w.x + v.y * w.y + v.z * w.z + v.w * w.w;
    }
    asrc[idx] = s1;
    adst[idx] = s2;
}

// One wave per destination node: fused online-softmax aggregation, no atomics.
template <int H_, int C, bool RELU>
__global__ __launch_bounds__(256) void aggr_kernel(
    const float* __restrict__ hbuf, const float* __restrict__ asrc,
    const float* __restrict__ adst, const float* __restrict__ bias,
    const int* __restrict__ offsets, const int* __restrict__ ssrc,
    float* __restrict__ out, int N) {
    constexpr int FOUT = H_ * C;
    constexpr int PER = FOUT / 64;
    int wid = threadIdx.x >> 6;
    int lane = threadIdx.x & 63;
    int n = blockIdx.x * 4 + wid;
    if (n >= N) return;
    int c0 = lane * PER;
    int head = c0 / C;

    float adst_h = adst[n * H_ + head];
    float m = lrelu(asrc[n * H_ + head] + adst_h);
    float D = 1.f;
    float S0, S1 = 0.f;
    if (PER == 2) {
        float2 hv = *(const float2*)&hbuf[(size_t)n * FOUT + c0];
        S0 = hv.x;
        S1 = hv.y;
    } else {
        S0 = hbuf[(size_t)n * FOUT + c0];
    }

    int k = offsets[n];
    const int e1 = offsets[n + 1];

    for (; k + 4 <= e1; k += 4) {
        int s0 = ssrc[k], s1 = ssrc[k + 1], s2 = ssrc[k + 2], s3 = ssrc[k + 3];
        float2 h0, h1, h2, h3;
        float g0 = 0.f, g1 = 0.f, g2 = 0.f, g3 = 0.f;
        if (PER == 2) {
            h0 = *(const float2*)&hbuf[(size_t)s0 * FOUT + c0];
            h1 = *(const float2*)&hbuf[(size_t)s1 * FOUT + c0];
            h2 = *(const float2*)&hbuf[(size_t)s2 * FOUT + c0];
            h3 = *(const float2*)&hbuf[(size_t)s3 * FOUT + c0];
        } else {
            g0 = hbuf[(size_t)s0 * FOUT + c0];
            g1 = hbuf[(size_t)s1 * FOUT + c0];
            g2 = hbuf[(size_t)s2 * FOUT + c0];
            g3 = hbuf[(size_t)s3 * FOUT + c0];
        }
        float E0 = lrelu(asrc[s0 * H_ + head] + adst_h);
        float E1 = lrelu(asrc[s1 * H_ + head] + adst_h);
        float E2 = lrelu(asrc[s2 * H_ + head] + adst_h);
        float E3 = lrelu(asrc[s3 * H_ + head] + adst_h);
        float mn = fmaxf(m, fmaxf(fmaxf(E0, E1), fmaxf(E2, E3)));
        float sc = __expf(m - mn);
        m = mn;
        D *= sc;
        S0 *= sc;
        if (PER == 2) S1 *= sc;
        float x0 = __expf(E0 - m), x1 = __expf(E1 - m);
        float x2 = __expf(E2 - m), x3 = __expf(E3 - m);
        D += (x0 + x1) + (x2 + x3);
        if (PER == 2) {
            S0 += x0 * h0.x + x1 * h1.x + x2 * h2.x + x3 * h3.x;
            S1 += x0 * h0.y + x1 * h1.y + x2 * h2.y + x3 * h3.y;
        } else {
            S0 += x0 * g0 + x1 * g1 + x2 * g2 + x3 * g3;
        }
    }
    for (; k < e1; ++k) {
        int s = ssrc[k];
        float2 hv;
        float gv = 0.f;
        if (PER == 2) {
            hv = *(const float2*)&hbuf[(size_t)s * FOUT + c0];
        } else {
            gv = hbuf[(size_t)s * FOUT + c0];
        }
        float E = lrelu(asrc[s * H_ + head] + adst_h);
        float mn = fmaxf(m, E);
        float sc = __expf(m - mn);
        m = mn;
        D *= sc;
        S0 *= sc;
        if (PER == 2) S1 *= sc;
        float ex = __expf(E - m);
        D += ex;
        if (PER == 2) {
            S0 += ex * hv.x;
            S1 += ex * hv.y;
        } else {
            S0 += ex * gv;
        }
    }

    float inv = 1.f / (D + 1e-16f);
    float v0 = S0 * inv + bias[c0];
    if (RELU) v0 = fmaxf(v0, 0.f);
    if (PER == 2) {
        float v1 = S1 * inv + bias[c0 + 1];
        if (RELU) v1 = fmaxf(v1, 0.f);
        *(float2*)&out[(size_t)n * FOUT + c0] = make_float2(v0, v1);
    } else {
        out[(size_t)n * FOUT + c0] = v0;
    }
}

extern "C" void kernel_launch(void* const* d_in, const int* in_sizes, int n_in,
                              void* d_out, int out_size, void* d_ws, size_t ws_size,
                              hipStream_t stream) {
    const float* x = (const float*)d_in[0];
    const int* ei = (const int*)d_in[1];
    const float* W0 = (const float*)d_in[2];
    const float* as0 = (const float*)d_in[3];
    const float* ad0 = (const float*)d_in[4];
    const float* b0 = (const float*)d_in[5];
    const float* W1 = (const float*)d_in[6];
    const float* as1 = (const float*)d_in[7];
    const float* ad1 = (const float*)d_in[8];
    const float* b1 = (const float*)d_in[9];
    const float* W2 = (const float*)d_in[10];
    const float* as2 = (const float*)d_in[11];
    const float* ad2 = (const float*)d_in[12];
    const float* b2 = (const float*)d_in[13];

    const int N = in_sizes[0] / 128;  // 50000
    const int E = in_sizes[1] / 2;    // 800000
    const int NB = (N + 255) / 256;   // 196 scan blocks

    // workspace carve
    float* wsf = (float*)d_ws;
    float* hbuf = wsf;                         // N*128
    float* feat = hbuf + (size_t)N * 128;      // N*128
    float* aS = feat + (size_t)N * 128;        // N*4
    float* aD = aS + (size_t)N * 4;            // N*4
    int* counts = (int*)(aD + (size_t)N * 4);  // N
    int* offsets = counts + N;                 // N+1
    int* cursor = offsets + N + 1;             // N
    int* ssrc = cursor + N;                    // E
    int* bsums = ssrc + E;                     // NB
    int* bpre = bsums + NB;                    // NB

    // ---- CSR build (dst-sorted srcs), reused by all 3 layers ----
    fill_zero_kernel<<<(N + 255) / 256, 256, 0, stream>>>(counts, N);
    hist_kernel<<<(E + 255) / 256, 256, 0, stream>>>(ei, E, counts);
    block_reduce_kernel<<<NB, 256, 0, stream>>>(counts, N, bsums);
    scan_bsums_kernel<<<1, 256, 0, stream>>>(bsums, NB, bpre, offsets, N);
    write_offsets_kernel<<<NB, 256, 0, stream>>>(counts, N, bpre, offsets, cursor);
    scatter_kernel<<<(E + 255) / 256, 256, 0, stream>>>(ei, E, cursor, ssrc);

    const int gGemm = (N + 31) / 32;
    const int gAggr = (N + 3) / 4;

    // ---- layer 0 ----
    gemm_kernel<128><<<gGemm, 256, 0, stream>>>(x, W0, hbuf, N);
    alpha_kernel<4, 32><<<(N * 4 + 255) / 256, 256, 0, stream>>>(hbuf, as0, ad0, aS, aD, N);
    aggr_kernel<4, 32, true><<<gAggr, 256, 0, stream>>>(hbuf, aS, aD, b0, offsets, ssrc, feat, N);

    // ---- layer 1 ----
    gemm_kernel<128><<<gGemm, 256, 0, stream>>>(feat, W1, hbuf, N);
    alpha_kernel<4, 32><<<(N * 4 + 255) / 256, 256, 0, stream>>>(hbuf, as1, ad1, aS, aD, N);
    aggr_kernel<4, 32, true><<<gAggr, 256, 0, stream>>>(hbuf, aS, aD, b1, offsets, ssrc, feat, N);

    // ---- layer 2 ----
    gemm_kernel<64><<<gGemm, 256, 0, stream>>>(feat, W2, hbuf, N);
    alpha_kernel<1, 64><<<(N + 255) / 256, 256, 0, stream>>>(hbuf, as2, ad2, aS, aD, N);
    aggr_kernel<1, 64, false><<<gAggr, 256, 0, stream>>>(hbuf, aS, aD, b2, offsets, ssrc,
                                                         (float*)d_out, N);
}

// Round 4
// 388.591 us; speedup vs baseline: 2.1138x; 1.1981x over previous
//
#include <hip/hip_runtime.h>

// GAT encoder, 3 layers. N=50000, E=800000, Fin=128.
// R3 -> R4:
//  * GEMM rewritten as split-fp16 MFMA (x=hi+lo fp16; hi@hi+lo@hi+hi@lo via
//    mfma_f32_16x16x32_f16, ~2^-22 rel err). W pre-transposed+split once.
//  * h stored as fp16 only; alpha + aggr read fp16 (gather bytes halved).
//  * aggr (layers 0/1) emits next-layer input directly as fp16 hi/lo pair.

#define NEG_SLOPE 0.2f

typedef _Float16 f16;
typedef f16 f16x8 __attribute__((ext_vector_type(8)));
typedef f16 f16x4 __attribute__((ext_vector_type(4)));
typedef f16 f16x2 __attribute__((ext_vector_type(2)));
typedef float f32x4 __attribute__((ext_vector_type(4)));

__device__ __forceinline__ float lrelu(float v) { return v > 0.f ? v : NEG_SLOPE * v; }

// ---------------- CSR build ----------------

__global__ void fill_zero_kernel(int* __restrict__ p, int n) {
    int i = blockIdx.x * blockDim.x + threadIdx.x;
    if (i < n) p[i] = 0;
}

__global__ void hist_kernel(const int* __restrict__ ei, int E, int* __restrict__ counts) {
    int i = blockIdx.x * blockDim.x + threadIdx.x;
    if (i < E) atomicAdd(&counts[ei[E + i]], 1);  // row 1 = dst
}

__global__ __launch_bounds__(256) void block_reduce_kernel(const int* __restrict__ counts,
                                                           int N, int* __restrict__ bsums) {
    int i = blockIdx.x * 256 + threadIdx.x;
    int v = (i < N) ? counts[i] : 0;
#pragma unroll
    for (int off = 32; off > 0; off >>= 1) v += __shfl_xor(v, off);
    __shared__ int ws[4];
    if ((threadIdx.x & 63) == 0) ws[threadIdx.x >> 6] = v;
    __syncthreads();
    if (threadIdx.x == 0) bsums[blockIdx.x] = ws[0] + ws[1] + ws[2] + ws[3];
}

__global__ __launch_bounds__(256) void scan_bsums_kernel(const int* __restrict__ bsums, int nb,
                                                         int* __restrict__ bpre,
                                                         int* __restrict__ offsets, int N) {
    int tid = threadIdx.x;
    int chunk = (nb + 255) / 256;
    int b0 = tid * chunk, b1 = b0 + chunk;
    if (b0 > nb) b0 = nb;
    if (b1 > nb) b1 = nb;
    int s = 0;
    for (int i = b0; i < b1; ++i) s += bsums[i];
    int v = s;
    int lane = tid & 63, wid = tid >> 6;
#pragma unroll
    for (int off = 1; off < 64; off <<= 1) {
        int t = __shfl_up(v, off);
        if (lane >= off) v += t;
    }
    __shared__ int ws[4];
    if (lane == 63) ws[wid] = v;
    __syncthreads();
    int add = 0;
    for (int w = 0; w < wid; ++w) add += ws[w];
    v += add;
    int prefix = v - s;
    for (int i = b0; i < b1; ++i) {
        bpre[i] = prefix;
        prefix += bsums[i];
    }
    if (tid == 255) offsets[N] = v;
}

__global__ __launch_bounds__(256) void write_offsets_kernel(const int* __restrict__ counts,
                                                            int N, const int* __restrict__ bpre,
                                                            int* __restrict__ offsets,
                                                            int* __restrict__ cursor) {
    int i = blockIdx.x * 256 + threadIdx.x;
    int orig = (i < N) ? counts[i] : 0;
    int v = orig;
    int lane = threadIdx.x & 63, wid = threadIdx.x >> 6;
#pragma unroll
    for (int off = 1; off < 64; off <<= 1) {
        int t = __shfl_up(v, off);
        if (lane >= off) v += t;
    }
    __shared__ int ws[4];
    if (lane == 63) ws[wid] = v;
    __syncthreads();
    int add = bpre[blockIdx.x];
    for (int w = 0; w < wid; ++w) add += ws[w];
    int exc = v - orig + add;
    if (i < N) {
        offsets[i] = exc;
        cursor[i] = exc;
    }
}

__global__ void scatter_kernel(const int* __restrict__ ei, int E,
                               int* __restrict__ cursor, int* __restrict__ ssrc) {
    int i = blockIdx.x * blockDim.x + threadIdx.x;
    if (i < E) {
        int dst = ei[E + i];
        int pos = atomicAdd(&cursor[dst], 1);
        ssrc[pos] = ei[i];  // row 0 = src
    }
}

// ---------------- fp16 splits ----------------

// x (fp32) -> xh + xl (fp16 hi/lo). total4 = total_elems/4.
__global__ void split_x_kernel(const float* __restrict__ x, f16* __restrict__ xh,
                               f16* __restrict__ xl, int total4) {
    int i = blockIdx.x * blockDim.x + threadIdx.x;
    if (i >= total4) return;
    float4 v = *(const float4*)&x[(size_t)i * 4];
    float vv[4] = {v.x, v.y, v.z, v.w};
    f16x4 h, l;
#pragma unroll
    for (int j = 0; j < 4; ++j) {
        f16 hj = (f16)vv[j];
        h[j] = hj;
        l[j] = (f16)(vv[j] - (float)hj);
    }
    *(f16x4*)&xh[(size_t)i * 4] = h;
    *(f16x4*)&xl[(size_t)i * 4] = l;
}

// W0[128x128], W1[128x128], W2[128x64] fp32 -> transposed fp16 hi/lo [FOUT][128].
__global__ void split_w_kernel(const float* __restrict__ W0, const float* __restrict__ W1,
                               const float* __restrict__ W2, f16* __restrict__ w0h,
                               f16* __restrict__ w0l, f16* __restrict__ w1h,
                               f16* __restrict__ w1l, f16* __restrict__ w2h,
                               f16* __restrict__ w2l) {
    int idx = blockIdx.x * 256 + threadIdx.x;
    const float* W;
    f16 *oh, *ol;
    int k, c;
    if (idx < 16384) {
        W = W0; oh = w0h; ol = w0l; k = idx >> 7; c = idx & 127;
        float v = W[k * 128 + c];
        f16 h = (f16)v;
        oh[c * 128 + k] = h;
        ol[c * 128 + k] = (f16)(v - (float)h);
    } else if (idx < 32768) {
        int t = idx - 16384;
        W = W1; oh = w1h; ol = w1l; k = t >> 7; c = t & 127;
        float v = W[k * 128 + c];
        f16 h = (f16)v;
        oh[c * 128 + k] = h;
        ol[c * 128 + k] = (f16)(v - (float)h);
    } else if (idx < 40960) {
        int t = idx - 32768;
        W = W2; oh = w2h; ol = w2l; k = t >> 6; c = t & 63;
        float v = W[k * 64 + c];
        f16 h = (f16)v;
        oh[c * 128 + k] = h;
        ol[c * 128 + k] = (f16)(v - (float)h);
    }
}

// ---------------- split-fp16 MFMA GEMM ----------------
// H16[N,FOUT] (fp16) = (Ah+Al)[N,128] @ (Bh+Bl)[128,FOUT], 3-term split.
// B pre-transposed [FOUT][128]. Block = 4 waves = 64 rows, all FOUT cols.
// K staged in two 64-halves in LDS (pad 72 -> 2-way bank aliasing = free).
template <int FOUT>
__global__ __launch_bounds__(256) void gemm_mfma_kernel(
    const f16* __restrict__ Ah, const f16* __restrict__ Al, const f16* __restrict__ Bh,
    const f16* __restrict__ Bl, f16* __restrict__ H16, int N) {
    constexpr int CT = FOUT / 16;  // col-tiles: 8 or 4
    __shared__ f16 lw[2][FOUT][72];
    int tid = threadIdx.x;
    int w = tid >> 6, lane = tid & 63;
    int quad = lane >> 4, m = lane & 15;
    int row0 = blockIdx.x * 64 + w * 16;
    int arow = row0 + m;
    if (arow >= N) arow = N - 1;  // clamped rows never stored
    const f16* aph = &Ah[(size_t)arow * 128 + quad * 8];
    const f16* apl = &Al[(size_t)arow * 128 + quad * 8];

    f32x4 acc[CT];
#pragma unroll
    for (int t = 0; t < CT; ++t) acc[t] = (f32x4){0.f, 0.f, 0.f, 0.f};

    for (int kh = 0; kh < 2; ++kh) {
        __syncthreads();
        for (int f = tid; f < FOUT * 8; f += 256) {
            int col = f >> 3, ch = f & 7;
            *(f16x8*)&lw[0][col][ch * 8] = *(const f16x8*)&Bh[(size_t)col * 128 + kh * 64 + ch * 8];
            *(f16x8*)&lw[1][col][ch * 8] = *(const f16x8*)&Bl[(size_t)col * 128 + kh * 64 + ch * 8];
        }
        __syncthreads();
#pragma unroll
        for (int kc = 0; kc < 2; ++kc) {
            f16x8 fah = *(const f16x8*)&aph[kh * 64 + kc * 32];
            f16x8 fal = *(const f16x8*)&apl[kh * 64 + kc * 32];
#pragma unroll
            for (int t = 0; t < CT; ++t) {
                f16x8 fbh = *(const f16x8*)&lw[0][t * 16 + m][kc * 32 + quad * 8];
                f16x8 fbl = *(const f16x8*)&lw[1][t * 16 + m][kc * 32 + quad * 8];
                acc[t] = __builtin_amdgcn_mfma_f32_16x16x32_f16(fah, fbh, acc[t], 0, 0, 0);
                acc[t] = __builtin_amdgcn_mfma_f32_16x16x32_f16(fal, fbh, acc[t], 0, 0, 0);
                acc[t] = __builtin_amdgcn_mfma_f32_16x16x32_f16(fah, fbl, acc[t], 0, 0, 0);
            }
        }
    }
    // C/D layout: col = lane&15, row = quad*4 + reg  [guide-verified]
#pragma unroll
    for (int r = 0; r < 4; ++r) {
        int row = row0 + quad * 4 + r;
        if (row < N) {
#pragma unroll
            for (int t = 0; t < CT; ++t)
                H16[(size_t)row * FOUT + t * 16 + m] = (f16)acc[t][r];
        }
    }
}

// ---------------- alpha dots (reads fp16 h) ----------------
template <int H_, int C>
__global__ void alpha_kernel(const f16* __restrict__ h16, const float* __restrict__ a_src,
                             const float* __restrict__ a_dst, float* __restrict__ asrc,
                             float* __restrict__ adst, int N) {
    int idx = blockIdx.x * blockDim.x + threadIdx.x;
    if (idx >= N * H_) return;
    int n = idx / H_, h = idx % H_;
    const f16* hp = &h16[(size_t)n * H_ * C + h * C];
    const float* as = &a_src[h * C];
    const float* ad = &a_dst[h * C];
    float s1 = 0.f, s2 = 0.f;
#pragma unroll
    for (int c8 = 0; c8 < C / 8; ++c8) {
        f16x8 v = *(const f16x8*)&hp[c8 * 8];
#pragma unroll
        for (int j = 0; j < 8; ++j) {
            float vv = (float)v[j];
            s1 += vv * as[c8 * 8 + j];
            s2 += vv * ad[c8 * 8 + j];
        }
    }
    asrc[idx] = s1;
    adst[idx] = s2;
}

// ---------------- aggregation (fp16 gathers, online softmax) ----------------
// SPLIT_OUT: write fp16 hi/lo pair (feeds next MFMA gemm); else fp32 out.
template <int H_, int C, bool RELU, bool SPLIT_OUT>
__global__ __launch_bounds__(256) void aggr_kernel(
    const f16* __restrict__ h16, const float* __restrict__ asrc,
    const float* __restrict__ adst, const float* __restrict__ bias,
    const int* __restrict__ offsets, const int* __restrict__ ssrc, float* __restrict__ outf,
    f16* __restrict__ outh, f16* __restrict__ outl, int N) {
    constexpr int FOUT = H_ * C;
    constexpr int PER = FOUT / 64;  // 2 or 1
    int wid = threadIdx.x >> 6;
    int lane = threadIdx.x & 63;
    int n = blockIdx.x * 4 + wid;
    if (n >= N) return;
    int c0 = lane * PER;
    int head = c0 / C;

    float adst_h = adst[n * H_ + head];
    float m = lrelu(asrc[n * H_ + head] + adst_h);
    float D = 1.f;
    float S0, S1 = 0.f;
    if (PER == 2) {
        f16x2 hv = *(const f16x2*)&h16[(size_t)n * FOUT + c0];
        S0 = (float)hv[0];
        S1 = (float)hv[1];
    } else {
        S0 = (float)h16[(size_t)n * FOUT + c0];
    }

    int k = offsets[n];
    const int e1 = offsets[n + 1];

    for (; k + 4 <= e1; k += 4) {
        int s0 = ssrc[k], s1 = ssrc[k + 1], s2 = ssrc[k + 2], s3 = ssrc[k + 3];
        f16x2 h0, h1, h2, h3;
        float g0 = 0.f, g1 = 0.f, g2 = 0.f, g3 = 0.f;
        if (PER == 2) {
            h0 = *(const f16x2*)&h16[(size_t)s0 * FOUT + c0];
            h1 = *(const f16x2*)&h16[(size_t)s1 * FOUT + c0];
            h2 = *(const f16x2*)&h16[(size_t)s2 * FOUT + c0];
            h3 = *(const f16x2*)&h16[(size_t)s3 * FOUT + c0];
        } else {
            g0 = (float)h16[(size_t)s0 * FOUT + c0];
            g1 = (float)h16[(size_t)s1 * FOUT + c0];
            g2 = (float)h16[(size_t)s2 * FOUT + c0];
            g3 = (float)h16[(size_t)s3 * FOUT + c0];
        }
        float E0 = lrelu(asrc[s0 * H_ + head] + adst_h);
        float E1 = lrelu(asrc[s1 * H_ + head] + adst_h);
        float E2 = lrelu(asrc[s2 * H_ + head] + adst_h);
        float E3 = lrelu(asrc[s3 * H_ + head] + adst_h);
        float mn = fmaxf(m, fmaxf(fmaxf(E0, E1), fmaxf(E2, E3)));
        float sc = __expf(m - mn);
        m = mn;
        D *= sc;
        S0 *= sc;
        if (PER == 2) S1 *= sc;
        float x0 = __expf(E0 - m), x1 = __expf(E1 - m);
        float x2 = __expf(E2 - m), x3 = __expf(E3 - m);
        D += (x0 + x1) + (x2 + x3);
        if (PER == 2) {
            S0 += x0 * (float)h0[0] + x1 * (float)h1[0] + x2 * (float)h2[0] + x3 * (float)h3[0];
            S1 += x0 * (float)h0[1] + x1 * (float)h1[1] + x2 * (float)h2[1] + x3 * (float)h3[1];
        } else {
            S0 += x0 * g0 + x1 * g1 + x2 * g2 + x3 * g3;
        }
    }
    for (; k < e1; ++k) {
        int s = ssrc[k];
        f16x2 hv;
        float gv = 0.f;
        if (PER == 2) {
            hv = *(const f16x2*)&h16[(size_t)s * FOUT + c0];
        } else {
            gv = (float)h16[(size_t)s * FOUT + c0];
        }
        float E = lrelu(asrc[s * H_ + head] + adst_h);
        float mn = fmaxf(m, E);
        float sc = __expf(m - mn);
        m = mn;
        D *= sc;
        S0 *= sc;
        if (PER == 2) S1 *= sc;
        float ex = __expf(E - m);
        D += ex;
        if (PER == 2) {
            S0 += ex * (float)hv[0];
            S1 += ex * (float)hv[1];
        } else {
            S0 += ex * gv;
        }
    }

    float inv = 1.f / (D + 1e-16f);
    float v0 = S0 * inv + bias[c0];
    if (RELU) v0 = fmaxf(v0, 0.f);
    if (SPLIT_OUT) {
        float v1 = S1 * inv + bias[c0 + 1];
        if (RELU) v1 = fmaxf(v1, 0.f);
        f16 h0 = (f16)v0, h1 = (f16)v1;
        f16x2 hh = {h0, h1};
        f16x2 ll = {(f16)(v0 - (float)h0), (f16)(v1 - (float)h1)};
        *(f16x2*)&outh[(size_t)n * FOUT + c0] = hh;
        *(f16x2*)&outl[(size_t)n * FOUT + c0] = ll;
    } else if (PER == 2) {
        float v1 = S1 * inv + bias[c0 + 1];
        if (RELU) v1 = fmaxf(v1, 0.f);
        *(float2*)&outf[(size_t)n * FOUT + c0] = make_float2(v0, v1);
    } else {
        outf[(size_t)n * FOUT + c0] = v0;
    }
}

extern "C" void kernel_launch(void* const* d_in, const int* in_sizes, int n_in,
                              void* d_out, int out_size, void* d_ws, size_t ws_size,
                              hipStream_t stream) {
    const float* x = (const float*)d_in[0];
    const int* ei = (const int*)d_in[1];
    const float* W0 = (const float*)d_in[2];
    const float* as0 = (const float*)d_in[3];
    const float* ad0 = (const float*)d_in[4];
    const float* b0 = (const float*)d_in[5];
    const float* W1 = (const float*)d_in[6];
    const float* as1 = (const float*)d_in[7];
    const float* ad1 = (const float*)d_in[8];
    const float* b1 = (const float*)d_in[9];
    const float* W2 = (const float*)d_in[10];
    const float* as2 = (const float*)d_in[11];
    const float* ad2 = (const float*)d_in[12];
    const float* b2 = (const float*)d_in[13];

    const int N = in_sizes[0] / 128;  // 50000
    const int E = in_sizes[1] / 2;    // 800000
    const int NB = (N + 255) / 256;

    // workspace carve (all 16B-aligned)
    float* aS = (float*)d_ws;                  // N*4 f32
    float* aD = aS + (size_t)N * 4;            // N*4 f32
    f16* h16 = (f16*)(aD + (size_t)N * 4);     // N*128 f16
    f16* xh = h16 + (size_t)N * 128;           // N*128 f16 (layer input hi)
    f16* xl = xh + (size_t)N * 128;            // N*128 f16 (layer input lo)
    f16* w0h = xl + (size_t)N * 128;           // 128*128
    f16* w0l = w0h + 16384;
    f16* w1h = w0l + 16384;
    f16* w1l = w1h + 16384;
    f16* w2h = w1l + 16384;                    // 64*128
    f16* w2l = w2h + 8192;
    int* counts = (int*)(w2l + 8192);          // N
    int* offsets = counts + N;                 // N+1
    int* cursor = offsets + N + 1;             // N
    int* ssrc = cursor + N;                    // E
    int* bsums = ssrc + E;                     // NB
    int* bpre = bsums + NB;                    // NB

    // ---- CSR build ----
    fill_zero_kernel<<<(N + 255) / 256, 256, 0, stream>>>(counts, N);
    hist_kernel<<<(E + 255) / 256, 256, 0, stream>>>(ei, E, counts);
    block_reduce_kernel<<<NB, 256, 0, stream>>>(counts, N, bsums);
    scan_bsums_kernel<<<1, 256, 0, stream>>>(bsums, NB, bpre, offsets, N);
    write_offsets_kernel<<<NB, 256, 0, stream>>>(counts, N, bpre, offsets, cursor);
    scatter_kernel<<<(E + 255) / 256, 256, 0, stream>>>(ei, E, cursor, ssrc);

    // ---- splits ----
    split_x_kernel<<<(N * 32 + 255) / 256, 256, 0, stream>>>(x, xh, xl, N * 32);
    split_w_kernel<<<160, 256, 0, stream>>>(W0, W1, W2, w0h, w0l, w1h, w1l, w2h, w2l);

    const int gGemm = (N + 63) / 64;
    const int gAggr = (N + 3) / 4;

    // ---- layer 0 ----
    gemm_mfma_kernel<128><<<gGemm, 256, 0, stream>>>(xh, xl, w0h, w0l, h16, N);
    alpha_kernel<4, 32><<<(N * 4 + 255) / 256, 256, 0, stream>>>(h16, as0, ad0, aS, aD, N);
    aggr_kernel<4, 32, true, true><<<gAggr, 256, 0, stream>>>(h16, aS, aD, b0, offsets, ssrc,
                                                              nullptr, xh, xl, N);
    // ---- layer 1 ----
    gemm_mfma_kernel<128><<<gGemm, 256, 0, stream>>>(xh, xl, w1h, w1l, h16, N);
    alpha_kernel<4, 32><<<(N * 4 + 255) / 256, 256, 0, stream>>>(h16, as1, ad1, aS, aD, N);
    aggr_kernel<4, 32, true, true><<<gAggr, 256, 0, stream>>>(h16, aS, aD, b1, offsets, ssrc,
                                                              nullptr, xh, xl, N);
    // ---- layer 2 ----
    gemm_mfma_kernel<64><<<gGemm, 256, 0, stream>>>(xh, xl, w2h, w2l, h16, N);
    alpha_kernel<1, 64><<<(N + 255) / 256, 256, 0, stream>>>(h16, as2, ad2, aS, aD, N);
    aggr_kernel<1, 64, false, false><<<gAggr, 256, 0, stream>>>(h16, aS, aD, b2, offsets, ssrc,
                                                                (float*)d_out, nullptr, nullptr, N);
}

// Round 5
// 322.645 us; speedup vs baseline: 2.5459x; 1.2044x over previous
//
#include <hip/hip_runtime.h>

// GAT encoder, 3 layers. N=50000, E=800000, Fin=128.
// R4 -> R5: CSR build rewritten as a two-level counting sort
// (bucket_count -> bucket_scan -> bucket_scatter -> bucket_sort).
// Kills the 58us random-scatter kernel (53 MB of line-thrash writes) and the
// N-wide hist/scan pipeline (offsets now fall out of the per-bucket sort).
// Requires N < 65536 (src and dst-low pack into one u32). GEMM/alpha/aggr
// unchanged from R4.

#define NEG_SLOPE 0.2f

typedef _Float16 f16;
typedef f16 f16x8 __attribute__((ext_vector_type(8)));
typedef f16 f16x4 __attribute__((ext_vector_type(4)));
typedef f16 f16x2 __attribute__((ext_vector_type(2)));
typedef float f32x4 __attribute__((ext_vector_type(4)));

__device__ __forceinline__ float lrelu(float v) { return v > 0.f ? v : NEG_SLOPE * v; }

// ---------------- CSR build: two-level counting sort ----------------

__global__ void fill_zero_kernel(int* __restrict__ p, int n) {
    int i = blockIdx.x * blockDim.x + threadIdx.x;
    if (i < n) p[i] = 0;
}

// Level-1 histogram over coarse buckets (dst>>8). LDS-aggregated.
__global__ __launch_bounds__(256) void bucket_count_kernel(const int* __restrict__ dst, int E,
                                                           int* __restrict__ bcount) {
    __shared__ int lh[256];
    lh[threadIdx.x] = 0;
    __syncthreads();
    int stride = gridDim.x * 256 * 4;
    for (int i = (blockIdx.x * 256 + threadIdx.x) * 4; i < E; i += stride) {
        int4 d = *(const int4*)&dst[i];
        atomicAdd(&lh[d.x >> 8], 1);
        atomicAdd(&lh[d.y >> 8], 1);
        atomicAdd(&lh[d.z >> 8], 1);
        atomicAdd(&lh[d.w >> 8], 1);
    }
    __syncthreads();
    int v = lh[threadIdx.x];
    if (v > 0) atomicAdd(&bcount[threadIdx.x], v);
}

// Exclusive scan of NBK (<=256) bucket counts; seeds bcursor; offsets[N]=E.
__global__ __launch_bounds__(256) void bucket_scan_kernel(const int* __restrict__ bcount, int NBK,
                                                          int* __restrict__ bbase,
                                                          int* __restrict__ bcursor,
                                                          int* __restrict__ offsets, int N) {
    int t = threadIdx.x;
    int own = (t < NBK) ? bcount[t] : 0;
    int v = own;
    int lane = t & 63, wid = t >> 6;
#pragma unroll
    for (int off = 1; off < 64; off <<= 1) {
        int u = __shfl_up(v, off);
        if (lane >= off) v += u;
    }
    __shared__ int ws[4];
    if (lane == 63) ws[wid] = v;
    __syncthreads();
    int add = 0;
    for (int w = 0; w < wid; ++w) add += ws[w];
    v += add;            // inclusive
    int exc = v - own;
    if (t < NBK) {
        bbase[t] = exc;
        bcursor[t] = exc;
    }
    if (t == 255) {
        bbase[NBK] = v;   // = E
        offsets[N] = v;
    }
}

// Level-1 scatter into bucket-contiguous staging, LDS-ranked so each block's
// writes per bucket form a contiguous run. Record = src | (dst&255)<<16.
#define SC_TILE 4096  // 16 edges/thread
__global__ __launch_bounds__(256) void bucket_scatter_kernel(const int* __restrict__ src,
                                                             const int* __restrict__ dst, int E,
                                                             int* __restrict__ bcursor,
                                                             unsigned int* __restrict__ staging) {
    __shared__ int lh[256];
    __shared__ int lcur[256];
    int tid = threadIdx.x;
    lh[tid] = 0;
    __syncthreads();
    int base = blockIdx.x * SC_TILE + tid * 16;
    int sv[16], dv[16];
    bool act = base < E;  // E%16==0: runs fully in or out
    if (act) {
#pragma unroll
        for (int q = 0; q < 4; ++q) {
            *(int4*)&sv[q * 4] = *(const int4*)&src[base + q * 4];
            *(int4*)&dv[q * 4] = *(const int4*)&dst[base + q * 4];
        }
#pragma unroll
        for (int j = 0; j < 16; ++j) atomicAdd(&lh[dv[j] >> 8], 1);
    }
    __syncthreads();
    int c = lh[tid];
    if (c > 0) lcur[tid] = atomicAdd(&bcursor[tid], c);
    __syncthreads();
    if (act) {
#pragma unroll
        for (int j = 0; j < 16; ++j) {
            int b = dv[j] >> 8;
            int pos = atomicAdd(&lcur[b], 1);
            staging[pos] = (unsigned int)sv[j] | ((unsigned int)(dv[j] & 255) << 16);
        }
    }
}

// Level-2: one block per bucket. Local 256-hist + scan gives offsets[] for
// this bucket's 256 dsts AND the in-bucket reorder; ssrc written coalesced.
#define SORT_CAP 8192
__global__ __launch_bounds__(256) void bucket_sort_kernel(const unsigned int* __restrict__ staging,
                                                          const int* __restrict__ bbase,
                                                          int* __restrict__ offsets,
                                                          int* __restrict__ ssrc, int N) {
    __shared__ unsigned int buf[SORT_CAP];
    __shared__ unsigned short sout[SORT_CAP];
    __shared__ int lh[256];
    __shared__ int ws[4];
    int b = blockIdx.x;
    int tid = threadIdx.x;
    int s = bbase[b], e = bbase[b + 1];
    int cnt = e - s;
    lh[tid] = 0;
    __syncthreads();
    bool fits = cnt <= SORT_CAP;
    if (fits) {
        for (int i = tid; i < cnt; i += 256) {
            unsigned int rec = staging[s + i];
            buf[i] = rec;
            atomicAdd(&lh[rec >> 16], 1);
        }
    } else {  // rare fallback: hist from global
        for (int i = tid; i < cnt; i += 256) atomicAdd(&lh[staging[s + i] >> 16], 1);
    }
    __syncthreads();
    int own = lh[tid];
    int v = own;
    int lane = tid & 63, wid = tid >> 6;
#pragma unroll
    for (int off = 1; off < 64; off <<= 1) {
        int u = __shfl_up(v, off);
        if (lane >= off) v += u;
    }
    if (lane == 63) ws[wid] = v;
    __syncthreads();
    int add = 0;
    for (int w = 0; w < wid; ++w) add += ws[w];
    int exc = v + add - own;
    int dstn = (b << 8) + tid;
    if (dstn < N) offsets[dstn] = s + exc;
    __syncthreads();
    lh[tid] = exc;  // cursor
    __syncthreads();
    if (fits) {
        for (int i = tid; i < cnt; i += 256) {
            unsigned int rec = buf[i];
            int r = atomicAdd(&lh[rec >> 16], 1);
            sout[r] = (unsigned short)(rec & 0xFFFFu);
        }
        __syncthreads();
        for (int i = tid; i < cnt; i += 256) ssrc[s + i] = (int)sout[i];
    } else {
        for (int i = tid; i < cnt; i += 256) {
            unsigned int rec = staging[s + i];
            int r = atomicAdd(&lh[rec >> 16], 1);
            ssrc[s + r] = (int)(rec & 0xFFFFu);
        }
    }
}

// ---------------- fp16 splits ----------------

__global__ void split_x_kernel(const float* __restrict__ x, f16* __restrict__ xh,
                               f16* __restrict__ xl, int total4) {
    int i = blockIdx.x * blockDim.x + threadIdx.x;
    if (i >= total4) return;
    float4 v = *(const float4*)&x[(size_t)i * 4];
    float vv[4] = {v.x, v.y, v.z, v.w};
    f16x4 h, l;
#pragma unroll
    for (int j = 0; j < 4; ++j) {
        f16 hj = (f16)vv[j];
        h[j] = hj;
        l[j] = (f16)(vv[j] - (float)hj);
    }
    *(f16x4*)&xh[(size_t)i * 4] = h;
    *(f16x4*)&xl[(size_t)i * 4] = l;
}

__global__ void split_w_kernel(const float* __restrict__ W0, const float* __restrict__ W1,
                               const float* __restrict__ W2, f16* __restrict__ w0h,
                               f16* __restrict__ w0l, f16* __restrict__ w1h,
                               f16* __restrict__ w1l, f16* __restrict__ w2h,
                               f16* __restrict__ w2l) {
    int idx = blockIdx.x * 256 + threadIdx.x;
    if (idx < 16384) {
        int k = idx >> 7, c = idx & 127;
        float v = W0[k * 128 + c];
        f16 h = (f16)v;
        w0h[c * 128 + k] = h;
        w0l[c * 128 + k] = (f16)(v - (float)h);
    } else if (idx < 32768) {
        int t = idx - 16384;
        int k = t >> 7, c = t & 127;
        float v = W1[k * 128 + c];
        f16 h = (f16)v;
        w1h[c * 128 + k] = h;
        w1l[c * 128 + k] = (f16)(v - (float)h);
    } else if (idx < 40960) {
        int t = idx - 32768;
        int k = t >> 6, c = t & 63;
        float v = W2[k * 64 + c];
        f16 h = (f16)v;
        w2h[c * 128 + k] = h;
        w2l[c * 128 + k] = (f16)(v - (float)h);
    }
}

// ---------------- split-fp16 MFMA GEMM ----------------
template <int FOUT>
__global__ __launch_bounds__(256) void gemm_mfma_kernel(
    const f16* __restrict__ Ah, const f16* __restrict__ Al, const f16* __restrict__ Bh,
    const f16* __restrict__ Bl, f16* __restrict__ H16, int N) {
    constexpr int CT = FOUT / 16;
    __shared__ f16 lw[2][FOUT][72];
    int tid = threadIdx.x;
    int w = tid >> 6, lane = tid & 63;
    int quad = lane >> 4, m = lane & 15;
    int row0 = blockIdx.x * 64 + w * 16;
    int arow = row0 + m;
    if (arow >= N) arow = N - 1;
    const f16* aph = &Ah[(size_t)arow * 128 + quad * 8];
    const f16* apl = &Al[(size_t)arow * 128 + quad * 8];

    f32x4 acc[CT];
#pragma unroll
    for (int t = 0; t < CT; ++t) acc[t] = (f32x4){0.f, 0.f, 0.f, 0.f};

    for (int kh = 0; kh < 2; ++kh) {
        __syncthreads();
        for (int f = tid; f < FOUT * 8; f += 256) {
            int col = f >> 3, ch = f & 7;
            *(f16x8*)&lw[0][col][ch * 8] = *(const f16x8*)&Bh[(size_t)col * 128 + kh * 64 + ch * 8];
            *(f16x8*)&lw[1][col][ch * 8] = *(const f16x8*)&Bl[(size_t)col * 128 + kh * 64 + ch * 8];
        }
        __syncthreads();
#pragma unroll
        for (int kc = 0; kc < 2; ++kc) {
            f16x8 fah = *(const f16x8*)&aph[kh * 64 + kc * 32];
            f16x8 fal = *(const f16x8*)&apl[kh * 64 + kc * 32];
#pragma unroll
            for (int t = 0; t < CT; ++t) {
                f16x8 fbh = *(const f16x8*)&lw[0][t * 16 + m][kc * 32 + quad * 8];
                f16x8 fbl = *(const f16x8*)&lw[1][t * 16 + m][kc * 32 + quad * 8];
                acc[t] = __builtin_amdgcn_mfma_f32_16x16x32_f16(fah, fbh, acc[t], 0, 0, 0);
                acc[t] = __builtin_amdgcn_mfma_f32_16x16x32_f16(fal, fbh, acc[t], 0, 0, 0);
                acc[t] = __builtin_amdgcn_mfma_f32_16x16x32_f16(fah, fbl, acc[t], 0, 0, 0);
            }
        }
    }
#pragma unroll
    for (int r = 0; r < 4; ++r) {
        int row = row0 + quad * 4 + r;
        if (row < N) {
#pragma unroll
            for (int t = 0; t < CT; ++t)
                H16[(size_t)row * FOUT + t * 16 + m] = (f16)acc[t][r];
        }
    }
}

// ---------------- alpha dots ----------------
template <int H_, int C>
__global__ void alpha_kernel(const f16* __restrict__ h16, const float* __restrict__ a_src,
                             const float* __restrict__ a_dst, float* __restrict__ asrc,
                             float* __restrict__ adst, int N) {
    int idx = blockIdx.x * blockDim.x + threadIdx.x;
    if (idx >= N * H_) return;
    int n = idx / H_, h = idx % H_;
    const f16* hp = &h16[(size_t)n * H_ * C + h * C];
    const float* as = &a_src[h * C];
    const float* ad = &a_dst[h * C];
    float s1 = 0.f, s2 = 0.f;
#pragma unroll
    for (int c8 = 0; c8 < C / 8; ++c8) {
        f16x8 v = *(const f16x8*)&hp[c8 * 8];
#pragma unroll
        for (int j = 0; j < 8; ++j) {
            float vv = (float)v[j];
            s1 += vv * as[c8 * 8 + j];
            s2 += vv * ad[c8 * 8 + j];
        }
    }
    asrc[idx] = s1;
    adst[idx] = s2;
}

// ---------------- aggregation ----------------
template <int H_, int C, bool RELU, bool SPLIT_OUT>
__global__ __launch_bounds__(256) void aggr_kernel(
    const f16* __restrict__ h16, const float* __restrict__ asrc,
    const float* __restrict__ adst, const float* __restrict__ bias,
    const int* __restrict__ offsets, const int* __restrict__ ssrc, float* __restrict__ outf,
    f16* __restrict__ outh, f16* __restrict__ outl, int N) {
    constexpr int FOUT = H_ * C;
    constexpr int PER = FOUT / 64;
    int wid = threadIdx.x >> 6;
    int lane = threadIdx.x & 63;
    int n = blockIdx.x * 4 + wid;
    if (n >= N) return;
    int c0 = lane * PER;
    int head = c0 / C;

    float adst_h = adst[n * H_ + head];
    float m = lrelu(asrc[n * H_ + head] + adst_h);
    float D = 1.f;
    float S0, S1 = 0.f;
    if (PER == 2) {
        f16x2 hv = *(const f16x2*)&h16[(size_t)n * FOUT + c0];
        S0 = (float)hv[0];
        S1 = (float)hv[1];
    } else {
        S0 = (float)h16[(size_t)n * FOUT + c0];
    }

    int k = offsets[n];
    const int e1 = offsets[n + 1];

    for (; k + 4 <= e1; k += 4) {
        int s0 = ssrc[k], s1 = ssrc[k + 1], s2 = ssrc[k + 2], s3 = ssrc[k + 3];
        f16x2 h0, h1, h2, h3;
        float g0 = 0.f, g1 = 0.f, g2 = 0.f, g3 = 0.f;
        if (PER == 2) {
            h0 = *(const f16x2*)&h16[(size_t)s0 * FOUT + c0];
            h1 = *(const f16x2*)&h16[(size_t)s1 * FOUT + c0];
            h2 = *(const f16x2*)&h16[(size_t)s2 * FOUT + c0];
            h3 = *(const f16x2*)&h16[(size_t)s3 * FOUT + c0];
        } else {
            g0 = (float)h16[(size_t)s0 * FOUT + c0];
            g1 = (float)h16[(size_t)s1 * FOUT + c0];
            g2 = (float)h16[(size_t)s2 * FOUT + c0];
            g3 = (float)h16[(size_t)s3 * FOUT + c0];
        }
        float E0 = lrelu(asrc[s0 * H_ + head] + adst_h);
        float E1 = lrelu(asrc[s1 * H_ + head] + adst_h);
        float E2 = lrelu(asrc[s2 * H_ + head] + adst_h);
        float E3 = lrelu(asrc[s3 * H_ + head] + adst_h);
        float mn = fmaxf(m, fmaxf(fmaxf(E0, E1), fmaxf(E2, E3)));
        float sc = __expf(m - mn);
        m = mn;
        D *= sc;
        S0 *= sc;
        if (PER == 2) S1 *= sc;
        float x0 = __expf(E0 - m), x1 = __expf(E1 - m);
        float x2 = __expf(E2 - m), x3 = __expf(E3 - m);
        D += (x0 + x1) + (x2 + x3);
        if (PER == 2) {
            S0 += x0 * (float)h0[0] + x1 * (float)h1[0] + x2 * (float)h2[0] + x3 * (float)h3[0];
            S1 += x0 * (float)h0[1] + x1 * (float)h1[1] + x2 * (float)h2[1] + x3 * (float)h3[1];
        } else {
            S0 += x0 * g0 + x1 * g1 + x2 * g2 + x3 * g3;
        }
    }
    for (; k < e1; ++k) {
        int s = ssrc[k];
        f16x2 hv;
        float gv = 0.f;
        if (PER == 2) {
            hv = *(const f16x2*)&h16[(size_t)s * FOUT + c0];
        } else {
            gv = (float)h16[(size_t)s * FOUT + c0];
        }
        float E = lrelu(asrc[s * H_ + head] + adst_h);
        float mn = fmaxf(m, E);
        float sc = __expf(m - mn);
        m = mn;
        D *= sc;
        S0 *= sc;
        if (PER == 2) S1 *= sc;
        float ex = __expf(E - m);
        D += ex;
        if (PER == 2) {
            S0 += ex * (float)hv[0];
            S1 += ex * (float)hv[1];
        } else {
            S0 += ex * gv;
        }
    }

    float inv = 1.f / (D + 1e-16f);
    float v0 = S0 * inv + bias[c0];
    if (RELU) v0 = fmaxf(v0, 0.f);
    if (SPLIT_OUT) {
        float v1 = S1 * inv + bias[c0 + 1];
        if (RELU) v1 = fmaxf(v1, 0.f);
        f16 h0 = (f16)v0, h1 = (f16)v1;
        f16x2 hh = {h0, h1};
        f16x2 ll = {(f16)(v0 - (float)h0), (f16)(v1 - (float)h1)};
        *(f16x2*)&outh[(size_t)n * FOUT + c0] = hh;
        *(f16x2*)&outl[(size_t)n * FOUT + c0] = ll;
    } else if (PER == 2) {
        float v1 = S1 * inv + bias[c0 + 1];
        if (RELU) v1 = fmaxf(v1, 0.f);
        *(float2*)&outf[(size_t)n * FOUT + c0] = make_float2(v0, v1);
    } else {
        outf[(size_t)n * FOUT + c0] = v0;
    }
}

extern "C" void kernel_launch(void* const* d_in, const int* in_sizes, int n_in,
                              void* d_out, int out_size, void* d_ws, size_t ws_size,
                              hipStream_t stream) {
    const float* x = (const float*)d_in[0];
    const int* ei = (const int*)d_in[1];
    const float* W0 = (const float*)d_in[2];
    const float* as0 = (const float*)d_in[3];
    const float* ad0 = (const float*)d_in[4];
    const float* b0 = (const float*)d_in[5];
    const float* W1 = (const float*)d_in[6];
    const float* as1 = (const float*)d_in[7];
    const float* ad1 = (const float*)d_in[8];
    const float* b1 = (const float*)d_in[9];
    const float* W2 = (const float*)d_in[10];
    const float* as2 = (const float*)d_in[11];
    const float* ad2 = (const float*)d_in[12];
    const float* b2 = (const float*)d_in[13];

    const int N = in_sizes[0] / 128;   // 50000
    const int E = in_sizes[1] / 2;     // 800000
    const int NBK = (N + 255) >> 8;    // 196 coarse buckets (N < 65536)

    // workspace carve (all 16B-aligned)
    float* aS = (float*)d_ws;                  // N*4 f32
    float* aD = aS + (size_t)N * 4;            // N*4 f32
    f16* h16 = (f16*)(aD + (size_t)N * 4);     // N*128 f16
    f16* xh = h16 + (size_t)N * 128;           // N*128 f16
    f16* xl = xh + (size_t)N * 128;            // N*128 f16
    f16* w0h = xl + (size_t)N * 128;           // 128*128
    f16* w0l = w0h + 16384;
    f16* w1h = w0l + 16384;
    f16* w1l = w1h + 16384;
    f16* w2h = w1l + 16384;                    // 64*128
    f16* w2l = w2h + 8192;
    int* offsets = (int*)(w2l + 8192);         // N+1
    int* ssrc = offsets + N + 1;               // E
    unsigned int* staging = (unsigned int*)(ssrc + E);  // E
    int* bcount = (int*)(staging + E);         // NBK
    int* bbase = bcount + NBK;                 // NBK+1
    int* bcursor = bbase + NBK + 1;            // NBK

    // ---- CSR build: two-level counting sort ----
    fill_zero_kernel<<<1, 256, 0, stream>>>(bcount, NBK);
    bucket_count_kernel<<<196, 256, 0, stream>>>(ei + E, E, bcount);
    bucket_scan_kernel<<<1, 256, 0, stream>>>(bcount, NBK, bbase, bcursor, offsets, N);
    bucket_scatter_kernel<<<(E + SC_TILE - 1) / SC_TILE, 256, 0, stream>>>(ei, ei + E, E, bcursor,
                                                                           staging);
    bucket_sort_kernel<<<NBK, 256, 0, stream>>>(staging, bbase, offsets, ssrc, N);

    // ---- splits ----
    split_x_kernel<<<(N * 32 + 255) / 256, 256, 0, stream>>>(x, xh, xl, N * 32);
    split_w_kernel<<<160, 256, 0, stream>>>(W0, W1, W2, w0h, w0l, w1h, w1l, w2h, w2l);

    const int gGemm = (N + 63) / 64;
    const int gAggr = (N + 3) / 4;

    // ---- layer 0 ----
    gemm_mfma_kernel<128><<<gGemm, 256, 0, stream>>>(xh, xl, w0h, w0l, h16, N);
    alpha_kernel<4, 32><<<(N * 4 + 255) / 256, 256, 0, stream>>>(h16, as0, ad0, aS, aD, N);
    aggr_kernel<4, 32, true, true><<<gAggr, 256, 0, stream>>>(h16, aS, aD, b0, offsets, ssrc,
                                                              nullptr, xh, xl, N);
    // ---- layer 1 ----
    gemm_mfma_kernel<128><<<gGemm, 256, 0, stream>>>(xh, xl, w1h, w1l, h16, N);
    alpha_kernel<4, 32><<<(N * 4 + 255) / 256, 256, 0, stream>>>(h16, as1, ad1, aS, aD, N);
    aggr_kernel<4, 32, true, true><<<gAggr, 256, 0, stream>>>(h16, aS, aD, b1, offsets, ssrc,
                                                              nullptr, xh, xl, N);
    // ---- layer 2 ----
    gemm_mfma_kernel<64><<<gGemm, 256, 0, stream>>>(xh, xl, w2h, w2l, h16, N);
    alpha_kernel<1, 64><<<(N + 255) / 256, 256, 0, stream>>>(h16, as2, ad2, aS, aD, N);
    aggr_kernel<1, 64, false, false><<<gAggr, 256, 0, stream>>>(h16, aS, aD, b2, offsets, ssrc,
                                                                (float*)d_out, nullptr, nullptr, N);
}